// Round 5
// baseline (6743.959 us; speedup 1.0000x reference)
//
#include <hip/hip_runtime.h>

#define BDIM 256   // batch
#define SDIM 512   // seq len
#define HDIM 512   // hidden
#define VDIM 128   // vocab
#define NBG 8      // batch groups
#define BB 32      // batch per group
#define HHU 16     // hidden units per block (hs slice)
#define WIHP 72    // col-major W_ih pitch (halfwords) per vocab row
#define NT 256     // 4 waves: w0,w1 gates; w2 stage-only; w3 proj

typedef unsigned short ushort_t;
typedef unsigned long long u64_t;
typedef __attribute__((ext_vector_type(8))) short bf16x8;
typedef __attribute__((ext_vector_type(4))) float f32x4;
typedef __attribute__((ext_vector_type(16))) float f32x16;

__device__ __forceinline__ ushort_t f2bf(float x) {
  unsigned u = __builtin_bit_cast(unsigned, x);
  u += 0x7fffu + ((u >> 16) & 1u);
  return (ushort_t)(u >> 16);
}
__device__ __forceinline__ float bf2f(ushort_t b) {
  unsigned u = ((unsigned)b) << 16;
  return __builtin_bit_cast(float, u);
}
__device__ __forceinline__ float sigmoidf_(float x) { return 1.f / (1.f + __expf(-x)); }
__device__ __forceinline__ float tanhf_(float x) { return 2.f / (1.f + __expf(-2.f * x)) - 1.f; }

// ---- weight loading -------------------------------------------------------
// Gate A-fragments for mfma_32x32x16: lane m=lane&31 holds A row m, k-octet
// half=lane>>5. Row m decodes (g=m&3, h=(m>>2)&1, s=m>>3) -> unit 2s+h.
__device__ __forceinline__ void load_afrag32(bf16x8* af, const float* Whh, int hs, int w,
                                             int lane) {
  const int m = lane & 31, half = lane >> 5;
  const int g = m & 3, hh = (m >> 2) & 1, s = m >> 3;
  const int gr = g * HDIM + hs * HHU + w * 8 + 2 * s + hh;
  const float* row = Whh + (size_t)gr * HDIM + half * 8;
#pragma unroll
  for (int kt = 0; kt < 32; ++kt) {
    const float4 f0 = *(const float4*)(row + kt * 16);
    const float4 f1 = *(const float4*)(row + kt * 16 + 4);
    bf16x8 v;
    v[0] = (short)f2bf(f0.x); v[1] = (short)f2bf(f0.y);
    v[2] = (short)f2bf(f0.z); v[3] = (short)f2bf(f0.w);
    v[4] = (short)f2bf(f1.x); v[5] = (short)f2bf(f1.y);
    v[6] = (short)f2bf(f1.z); v[7] = (short)f2bf(f1.w);
    af[kt] = v;
  }
}
// Proj A-fragments for mfma_16x16x32 (rows 0..3 valid = vocab hs*4+row).
__device__ __forceinline__ void load_afrag16(bf16x8* af, const float* W, int gr, int ko,
                                             bool valid) {
  const float* row = W + (size_t)gr * HDIM;
#pragma unroll
  for (int kt = 0; kt < 16; ++kt) {
    bf16x8 v;
    if (valid) {
      const float4 f0 = *(const float4*)(row + kt * 32 + ko);
      const float4 f1 = *(const float4*)(row + kt * 32 + ko + 4);
      v[0] = (short)f2bf(f0.x); v[1] = (short)f2bf(f0.y);
      v[2] = (short)f2bf(f0.z); v[3] = (short)f2bf(f0.w);
      v[4] = (short)f2bf(f1.x); v[5] = (short)f2bf(f1.y);
      v[6] = (short)f2bf(f1.z); v[7] = (short)f2bf(f1.w);
    } else {
#pragma unroll
      for (int j = 0; j < 8; ++j) v[j] = 0;
    }
    af[kt] = v;
  }
}
// W_ih column-major [vocab][64 gate-cols], col = (w*2+h)*16 + s*4 + g, + bias.
__device__ __forceinline__ void load_wih_cm(ushort_t* wih_s, float* bias_s, const float* Wih,
                                            const float* bi, const float* bh, int hs,
                                            int tid) {
  for (int c = tid; c < 128 * 64; c += NT) {
    int v = c & 127, col = c >> 7;
    int g = col & 3, s = (col >> 2) & 3, hh = (col >> 4) & 1, wv = col >> 5;
    int gr = g * HDIM + hs * HHU + wv * 8 + 2 * s + hh;
    wih_s[v * WIHP + col] = f2bf(Wih[(size_t)gr * VDIM + v]);
  }
  if (tid < 64) {
    int col = tid;
    int g = col & 3, s = (col >> 2) & 3, hh = (col >> 4) & 1, wv = col >> 5;
    int gr = g * HDIM + hs * HHU + wv * 8 + 2 * s + hh;
    bias_s[col] = bi[gr] + bh[gr];
  }
}

// Sync protocol (R5): per-WAVE flags + distributed stage, ONE barrier/step.
//  producer gate wave: 1 h-qword store/lane (sc1, LLC) -> s_waitcnt vmcnt(0)
//    (inline asm, wave-level) -> lane0 stores flags[bg][hs][w] = t+1.
//  consumer: wave w polls only its 8 producers' 16 wave-flags (64B coalesced),
//    stages their 8 KB (producer-major layout: 16B/lane/producer) into
//    double-buffered swizzled h_s[t&1], then ONE __syncthreads -> compute.
//  Buffer-alternation safety: a wave entering stage t+1 passed barrier t,
//    which implies every wave finished compute t-1 (readers of that buffer).
__global__ void __launch_bounds__(NT, 1) lstm_kernel(
    const int* __restrict__ C_idx, const int* __restrict__ E,
    const float* __restrict__ eWih, const float* __restrict__ eWhh,
    const float* __restrict__ ebi, const float* __restrict__ ebh,
    const float* __restrict__ dWih, const float* __restrict__ dWhh,
    const float* __restrict__ dbi, const float* __restrict__ dbh,
    const float* __restrict__ pW, const float* __restrict__ pb,
    unsigned* flags, u64_t* hbq, ushort_t* logits) {
  __shared__ ushort_t h_s[2][BB * HDIM];      // 2 x 32 KB, octet-swizzled
  __shared__ ushort_t wih_s[VDIM * WIHP];     // 18 KB, col-major
  __shared__ unsigned char idx8_s[1024 * BB]; // 32 KB: all step indices, u8
  __shared__ float bias_s[64];
  __shared__ float pb_s[4];

  const int tid = threadIdx.x;
  const int w = tid >> 6;
  const int lane = tid & 63;
  const int bg = blockIdx.x & 7;  // one batch group per XCD under round-robin
  const int hs = blockIdx.x >> 3;

  // persistent per-lane state
  bf16x8 afrag[32];  // gate waves: 32 K-chunks (128 VGPR). proj wave: 16 used.
  float cst[4] = {0.f, 0.f, 0.f, 0.f};
  if (w < 2) {
    load_afrag32(afrag, eWhh, hs, w, lane);
  } else if (w == 3) {
    load_afrag16(afrag, pW, hs * 4 + (lane & 15), (lane >> 4) * 8, (lane & 15) < 4);
  }
  load_wih_cm(wih_s, bias_s, eWih, ebi, ebh, hs, tid);
  if (tid < 4) pb_s[tid] = pb[hs * 4 + tid];
  // preload ALL 1024 step indices for this bg as u8 (values < 128)
  for (int c = tid; c < 1024 * BB; c += NT) {
    int t = c >> 5, b = c & 31;
    int v = (t < 512) ? C_idx[(size_t)(bg * BB + b) * SDIM + t]
                      : E[(size_t)(bg * BB + b) * (SDIM + 1) + (t - 512)];
    idx8_s[c] = (unsigned char)v;
  }
  __syncthreads();

  for (int t = 0; t <= 1024; ++t) {
    const bool last = (t == 1024);
    const int tb = t & 1;

    if (t == 512) {  // phase switch: barrier-protected wih_s reload + afrag
      __syncthreads();  // all waves done reading encoder wih_s (compute 511)
      load_wih_cm(wih_s, bias_s, dWih, dbi, dbh, hs, tid);
      if (w < 2) load_afrag32(afrag, dWhh, hs, w, lane);
      __syncthreads();  // wih_s writes visible before compute-512 gathers
    }

    // poll: wave w waits only its 8 producers' 16 wave-flags
    {
      const unsigned tgt = (unsigned)t;
      const unsigned* fp = flags + bg * 64 + w * 16 + (lane & 15);
      int rounds = 0;
      while (true) {
        unsigned f = (lane < 16)
            ? __hip_atomic_load(fp, __ATOMIC_RELAXED, __HIP_MEMORY_SCOPE_AGENT)
            : 0xFFFFFFFFu;
        if (__ballot(f >= tgt) == ~0ull) break;
        if (++rounds > (1 << 20)) break;  // bailout (never hit if co-resident)
      }
    }
    // stage this wave's 8 producers: 16B/lane/producer, producer-major layout
    {
      u64_t ta[8], tc[8];
      const u64_t* sb = hbq + (((size_t)tb * 256) + bg * 32 + w * 8) * 128 + lane * 2;
#pragma unroll
      for (int j = 0; j < 8; ++j) {
        ta[j] = __hip_atomic_load(sb + j * 128, __ATOMIC_RELAXED, __HIP_MEMORY_SCOPE_AGENT);
        tc[j] = __hip_atomic_load(sb + j * 128 + 1, __ATOMIC_RELAXED,
                                  __HIP_MEMORY_SCOPE_AGENT);
      }
      const int b = lane >> 1, jh = lane & 1;
#pragma unroll
      for (int j = 0; j < 8; ++j) {
        int ph = (((w * 8 + j) * 2 + jh) ^ (b & 7));
        ushort_t* d = &h_s[tb][b * HDIM + ph * 8];
        *(u64_t*)d = ta[j];
        *(u64_t*)(d + 4) = tc[j];
      }
    }
    __syncthreads();  // h_s[tb] complete across waves

    if (w < 2 && !last) {
      // gates: D[64 gate-rows x 32 batches], 2 waves of mfma_32x32x16,
      // two independent accumulator chains (halve dependent-MFMA latency)
      const int b = lane & 31, half = lane >> 5;
      const int w2h = w * 2 + half;
      f32x16 acc, acc2;
      {
        const int id0 = idx8_s[t * 32 + b];
        const ushort_t* wp = &wih_s[id0 * WIHP + w2h * 16];
        bf16x8 g0 = *(const bf16x8*)wp;
        bf16x8 g1 = *(const bf16x8*)(wp + 8);
#pragma unroll
        for (int r = 0; r < 8; ++r) {
          acc[r] = bias_s[w2h * 16 + r] + bf2f((ushort_t)g0[r]);
          acc[8 + r] = bias_s[w2h * 16 + 8 + r] + bf2f((ushort_t)g1[r]);
          acc2[r] = 0.f;
          acc2[8 + r] = 0.f;
        }
      }
      const ushort_t* hrow = &h_s[tb][b * HDIM];
      const int bx = b & 7;
#pragma unroll
      for (int kt = 0; kt < 16; ++kt) {
        bf16x8 b0 = *(const bf16x8*)(hrow + ((4 * kt + half) ^ bx) * 8);
        bf16x8 b1 = *(const bf16x8*)(hrow + ((4 * kt + 2 + half) ^ bx) * 8);
        acc = __builtin_amdgcn_mfma_f32_32x32x16_bf16(afrag[2 * kt], b0, acc, 0, 0, 0);
        acc2 = __builtin_amdgcn_mfma_f32_32x32x16_bf16(afrag[2 * kt + 1], b1, acc2, 0, 0, 0);
      }
      // acc[s*4+g] += acc2: gate g, unit 2s+half (of wave's 8 units), batch b
      unsigned hv[4];
#pragma unroll
      for (int s = 0; s < 4; ++s) {
        float ig = acc[s * 4 + 0] + acc2[s * 4 + 0];
        float fg = acc[s * 4 + 1] + acc2[s * 4 + 1];
        float gg = acc[s * 4 + 2] + acc2[s * 4 + 2];
        float og = acc[s * 4 + 3] + acc2[s * 4 + 3];
        float cn = sigmoidf_(fg) * cst[s] + sigmoidf_(ig) * tanhf_(gg);
        cst[s] = cn;
        hv[s] = f2bf(sigmoidf_(og) * tanhf_(cn));
      }
      u64_t own = (u64_t)hv[0] | ((u64_t)hv[1] << 16) | ((u64_t)hv[2] << 32) |
                  ((u64_t)hv[3] << 48);
      u64_t par = (u64_t)__shfl_xor((long long)own, 32, 64);  // partner: half^1
      u64_t out = 0;
#pragma unroll
      for (int j = 0; j < 4; ++j) {  // pack units 4*half+j of this wave's group
        int u4 = 4 * half + j;
        int sidx = 2 * half + (j >> 1);
        u64_t sv = ((u4 & 1) == half) ? own : par;
        out |= ((sv >> (16 * sidx)) & 0xFFFFull) << (16 * j);
      }
      // producer-major: slice (buf,hs) contiguous 128 qwords; quad = w*2+half
      __hip_atomic_store(
          hbq + (((size_t)((t + 1) & 1) * 256) + bg * 32 + hs) * 128 + b * 4 + w * 2 + half,
          out, __ATOMIC_RELAXED, __HIP_MEMORY_SCOPE_AGENT);
      __asm__ volatile("s_waitcnt vmcnt(0)" ::: "memory");  // this wave's h at LLC
      if (lane == 0)
        __hip_atomic_store(&flags[bg * 64 + hs * 2 + w], (unsigned)(t + 1),
                           __ATOMIC_RELAXED, __HIP_MEMORY_SCOPE_AGENT);
    } else if (w == 3 && t >= 513) {
      // proj: vocab rows hs*4..hs*4+3 x 32 batches, 2 tiles of mfma_16x16x32
      const int n = lane & 15, q = lane >> 4;
      f32x4 acc0 = {0.f, 0.f, 0.f, 0.f};
      f32x4 acc1 = {0.f, 0.f, 0.f, 0.f};
#pragma unroll
      for (int kt = 0; kt < 16; ++kt) {
        const int po0 = ((kt * 4 + q) ^ (n & 7)) * 8;
        bf16x8 b0 = *(const bf16x8*)&h_s[tb][n * HDIM + po0];
        bf16x8 b1 = *(const bf16x8*)&h_s[tb][(16 + n) * HDIM + po0];
        acc0 = __builtin_amdgcn_mfma_f32_16x16x32_bf16(afrag[kt], b0, acc0, 0, 0, 0);
        acc1 = __builtin_amdgcn_mfma_f32_16x16x32_bf16(afrag[kt], b1, acc1, 0, 0, 0);
      }
      if (q == 0) {  // rows 0..3 = reg = vocab hs*4+reg
        const int ld = t - 513;
        u64_t q0 = 0, q1 = 0;
#pragma unroll
        for (int r = 0; r < 4; ++r) {
          q0 |= (u64_t)f2bf(acc0[r] + pb_s[r]) << (16 * r);
          q1 |= (u64_t)f2bf(acc1[r] + pb_s[r]) << (16 * r);
        }
        u64_t* lq = (u64_t*)logits;
        const size_t base = ((size_t)ld * BDIM + bg * BB) * 32 + hs;
        lq[base + (size_t)n * 32] = q0;
        lq[base + (size_t)(16 + n) * 32] = q1;
      }
    }
    // no trailing barrier: h_s double-buffer + flag protocol cover reuse
  }
}

__global__ void loss_kernel(const ushort_t* __restrict__ logits, const int* __restrict__ E,
                            float* __restrict__ partial) {
  const int t = blockIdx.x;   // 512
  const int b = threadIdx.x;  // 256
  const ushort_t* row = logits + ((size_t)t * BDIM + b) * VDIM;
  float mx = -3.0e38f;
  for (int k = 0; k < VDIM; ++k) mx = fmaxf(mx, bf2f(row[k]));
  float se = 0.f;
  for (int k = 0; k < VDIM; ++k) se += __expf(bf2f(row[k]) - mx);
  const int tgt = E[(size_t)b * (SDIM + 1) + t];
  float nll = (mx + __logf(se)) - bf2f(row[tgt]);
  float m = (tgt != 0) ? 1.f : 0.f;
  __shared__ float s1[BDIM];
  __shared__ float s0[BDIM];
  s1[b] = nll * m;
  s0[b] = m;
  __syncthreads();
  for (int s = 128; s > 0; s >>= 1) {
    if (b < s) {
      s1[b] += s1[b + s];
      s0[b] += s0[b + s];
    }
    __syncthreads();
  }
  if (b == 0) partial[t] = (s0[0] > 0.f) ? s1[0] / s0[0] : 0.f;
}

__global__ void reduce_kernel(const float* __restrict__ partial, float* __restrict__ out) {
  __shared__ float sm[SDIM];
  sm[threadIdx.x] = partial[threadIdx.x];
  __syncthreads();
  for (int s = 256; s > 0; s >>= 1) {
    if (threadIdx.x < s) sm[threadIdx.x] += sm[threadIdx.x + s];
    __syncthreads();
  }
  if (threadIdx.x == 0) out[0] = sm[0];
}

extern "C" void kernel_launch(void* const* d_in, const int* in_sizes, int n_in,
                              void* d_out, int out_size, void* d_ws, size_t ws_size,
                              hipStream_t stream) {
  const int* C_idx = (const int*)d_in[0];
  const int* E = (const int*)d_in[1];
  const float* eWih = (const float*)d_in[2];
  const float* eWhh = (const float*)d_in[3];
  const float* ebi = (const float*)d_in[4];
  const float* ebh = (const float*)d_in[5];
  const float* dWih = (const float*)d_in[6];
  const float* dWhh = (const float*)d_in[7];
  const float* dbi = (const float*)d_in[8];
  const float* dbh = (const float*)d_in[9];
  const float* pW = (const float*)d_in[10];
  const float* pb = (const float*)d_in[11];

  char* ws = (char*)d_ws;
  unsigned* flags = (unsigned*)ws;                      // 8*64*4 B (pad to 4096)
  u64_t* hbq = (u64_t*)(ws + 4096);                     // 2*256*128*8 = 512 KiB
  ushort_t* logits = (ushort_t*)(ws + 4096 + 524288);   // 512*256*128*2 = 32 MiB
  float* partial = (float*)(ws + 4096 + 524288 + 33554432);  // 512*4 B

  // zero flags + h buffer 0 (h(0)=0); ws is poisoned 0xAA each call
  hipMemsetAsync(d_ws, 0, 4096 + 262144, stream);
  lstm_kernel<<<256, NT, 0, stream>>>(C_idx, E, eWih, eWhh, ebi, ebh, dWih, dWhh, dbi, dbh,
                                      pW, pb, flags, hbq, logits);
  loss_kernel<<<512, 256, 0, stream>>>(logits, E, partial);
  reduce_kernel<<<1, 512, 0, stream>>>(partial, (float*)d_out);
}

// Round 6
// 4300.144 us; speedup vs baseline: 1.5683x; 1.5683x over previous
//
#include <hip/hip_runtime.h>

#define BDIM 256   // batch
#define SDIM 512   // seq len
#define HDIM 512   // hidden
#define VDIM 128   // vocab
#define NBG 8      // batch groups
#define BB 32      // batch per group
#define HHU 16     // hidden units per block
#define WIHP 72    // col-major W_ih pitch (halfwords) per vocab row
#define NT 320     // 5 waves: w0,w1 gates; w2,w3 stage help; w4 proj

typedef unsigned short ushort_t;
typedef unsigned long long u64_t;
typedef __attribute__((ext_vector_type(8))) short bf16x8;
typedef __attribute__((ext_vector_type(4))) float f32x4;
typedef __attribute__((ext_vector_type(16))) float f32x16;

__device__ __forceinline__ ushort_t f2bf(float x) {
  unsigned u = __builtin_bit_cast(unsigned, x);
  u += 0x7fffu + ((u >> 16) & 1u);
  return (ushort_t)(u >> 16);
}
__device__ __forceinline__ float bf2f(ushort_t b) {
  unsigned u = ((unsigned)b) << 16;
  return __builtin_bit_cast(float, u);
}
__device__ __forceinline__ float sigmoidf_(float x) { return 1.f / (1.f + __expf(-x)); }
__device__ __forceinline__ float tanhf_(float x) { return 2.f / (1.f + __expf(-2.f * x)) - 1.f; }

// ---- weight loading -------------------------------------------------------
// Gate A-fragments for mfma_32x32x16: lane m=lane&31 holds A row m, k-octet
// half=lane>>5. Row m decodes (g=m&3, h=(m>>2)&1, s=m>>3) -> unit 2s+h.
__device__ __forceinline__ void load_afrag32(bf16x8* af, const float* Whh, int hs, int w,
                                             int lane) {
  const int m = lane & 31, half = lane >> 5;
  const int g = m & 3, hh = (m >> 2) & 1, s = m >> 3;
  const int gr = g * HDIM + hs * HHU + w * 8 + 2 * s + hh;
  const float* row = Whh + (size_t)gr * HDIM + half * 8;
#pragma unroll
  for (int kt = 0; kt < 32; ++kt) {
    const float4 f0 = *(const float4*)(row + kt * 16);
    const float4 f1 = *(const float4*)(row + kt * 16 + 4);
    bf16x8 v;
    v[0] = (short)f2bf(f0.x); v[1] = (short)f2bf(f0.y);
    v[2] = (short)f2bf(f0.z); v[3] = (short)f2bf(f0.w);
    v[4] = (short)f2bf(f1.x); v[5] = (short)f2bf(f1.y);
    v[6] = (short)f2bf(f1.z); v[7] = (short)f2bf(f1.w);
    af[kt] = v;
  }
}
// Proj A-fragments for mfma_16x16x32 (rows 0..3 valid = vocab hs*4+row).
__device__ __forceinline__ void load_afrag16(bf16x8* af, const float* W, int gr, int ko,
                                             bool valid) {
  const float* row = W + (size_t)gr * HDIM;
#pragma unroll
  for (int kt = 0; kt < 16; ++kt) {
    bf16x8 v;
    if (valid) {
      const float4 f0 = *(const float4*)(row + kt * 32 + ko);
      const float4 f1 = *(const float4*)(row + kt * 32 + ko + 4);
      v[0] = (short)f2bf(f0.x); v[1] = (short)f2bf(f0.y);
      v[2] = (short)f2bf(f0.z); v[3] = (short)f2bf(f0.w);
      v[4] = (short)f2bf(f1.x); v[5] = (short)f2bf(f1.y);
      v[6] = (short)f2bf(f1.z); v[7] = (short)f2bf(f1.w);
    } else {
#pragma unroll
      for (int j = 0; j < 8; ++j) v[j] = 0;
    }
    af[kt] = v;
  }
}
// W_ih column-major [vocab][64 gate-cols], col = (w*2+h)*16 + s*4 + g, + bias.
__device__ __forceinline__ void load_wih_cm(ushort_t* wih_s, float* bias_s, const float* Wih,
                                            const float* bi, const float* bh, int hs,
                                            int tid) {
  for (int c = tid; c < 128 * 64; c += NT) {
    int v = c & 127, col = c >> 7;
    int g = col & 3, s = (col >> 2) & 3, hh = (col >> 4) & 1, wv = col >> 5;
    int gr = g * HDIM + hs * HHU + wv * 8 + 2 * s + hh;
    wih_s[v * WIHP + col] = f2bf(Wih[(size_t)gr * VDIM + v]);
  }
  if (tid < 64) {
    int col = tid;
    int g = col & 3, s = (col >> 2) & 3, hh = (col >> 4) & 1, wv = col >> 5;
    int gr = g * HDIM + hs * HHU + wv * 8 + 2 * s + hh;
    bias_s[col] = bi[gr] + bh[gr];
  }
}

// Sync (R6 = R4 + early per-wave flags):
//  producer gate wave: 1 h-qword store/lane (agent, LLC) -> s_waitcnt vmcnt(0)
//    (wave-level) -> lane0 stores flags[bg][hs*2+w]=t+1 IMMEDIATELY (proj
//    compute / logits drain / block barrier are off the producer->flag path).
//  consumer: w0's 64 lanes poll the 64 wave-flags (256B coalesced) -> barrier
//    -> ALL 320 threads bulk-stage 32KB coalesced -> barrier -> compute.
//  Overwrite safety (2-step lag): publish(t+2) requires all h(t+1), which
//  requires every block's publish(t+1), which follows its stage(t).
__global__ void __launch_bounds__(NT, 1) lstm_kernel(
    const int* __restrict__ C_idx, const int* __restrict__ E,
    const float* __restrict__ eWih, const float* __restrict__ eWhh,
    const float* __restrict__ ebi, const float* __restrict__ ebh,
    const float* __restrict__ dWih, const float* __restrict__ dWhh,
    const float* __restrict__ dbi, const float* __restrict__ dbh,
    const float* __restrict__ pW, const float* __restrict__ pb,
    unsigned* flags, u64_t* hbq, ushort_t* logits) {
  __shared__ ushort_t h_s[BB * HDIM];       // 32 KB, octet-swizzled
  __shared__ ushort_t wih_s[VDIM * WIHP];   // 18 KB, col-major
  __shared__ float bias_s[64];
  __shared__ float pb_s[4];
  __shared__ int idx_s[2][BB];

  const int tid = threadIdx.x;
  const int w = tid >> 6;
  const int lane = tid & 63;
  const int bg = blockIdx.x & 7;  // one batch group per XCD under round-robin
  const int hs = blockIdx.x >> 3;

  // persistent per-lane state
  bf16x8 afrag[32];  // gate waves: 32 K-chunks (128 VGPR). proj wave: 16 used.
  float cst[4] = {0.f, 0.f, 0.f, 0.f};
  if (w < 2) {
    load_afrag32(afrag, eWhh, hs, w, lane);
  } else if (w == 4) {
    load_afrag16(afrag, pW, hs * 4 + (lane & 15), (lane >> 4) * 8, (lane & 15) < 4);
  }
  load_wih_cm(wih_s, bias_s, eWih, ebi, ebh, hs, tid);
  if (tid < 4) pb_s[tid] = pb[hs * 4 + tid];
  if (tid < BB) idx_s[0][tid] = C_idx[(size_t)(bg * BB + tid) * SDIM];
  __syncthreads();

  for (int t = 0; t <= 1024; ++t) {
    const bool last = (t == 1024);
    const bool proj_on = (t >= 513);

    if (t == 512) {  // phase switch (after trailing barrier of t=511)
      if (w < 2) load_afrag32(afrag, dWhh, hs, w, lane);
      load_wih_cm(wih_s, bias_s, dWih, dbi, dbh, hs, tid);
    }
    // prefetch idx for step t+1 (load now, LDS-write after stage barrier)
    int myidx = 0;
    const bool pf = (tid < BB) && (t + 1 < 1024);
    if (pf) {
      int tn = t + 1;
      myidx = (tn >= 512) ? E[(size_t)(bg * BB + tid) * (SDIM + 1) + (tn - 512)]
                          : C_idx[(size_t)(bg * BB + tid) * SDIM + tn];
    }

    // poll: w0's 64 lanes watch the bg's 64 per-wave flags (256B coalesced)
    if (t > 0 && w == 0) {
      const unsigned* fp = flags + bg * 64 + lane;
      const unsigned tgt = (unsigned)t;
      int rounds = 0;
      while (true) {
        unsigned f = __hip_atomic_load(fp, __ATOMIC_RELAXED, __HIP_MEMORY_SCOPE_AGENT);
        if (__ballot(f >= tgt) == ~0ull) break;
        if (++rounds > (1 << 20)) break;  // bailout (never hit if co-resident)
      }
    }
    __syncthreads();

    // stage h[32,512] bf16 (4096 u64) -> swizzled LDS, all 320 threads
    {
      const u64_t* src = hbq + ((size_t)(t & 1) * BDIM + bg * BB) * 128;
      u64_t tmp[13];
#pragma unroll
      for (int k = 0; k < 13; ++k) {
        int c = tid + k * NT;
        if (c < 4096)
          tmp[k] = __hip_atomic_load(src + c, __ATOMIC_RELAXED, __HIP_MEMORY_SCOPE_AGENT);
      }
#pragma unroll
      for (int k = 0; k < 13; ++k) {
        int c = tid + k * NT;
        if (c < 4096) {
          int m = c >> 7, k7 = c & 127;
          int p = (k7 >> 1) ^ (m & 7);
          *(u64_t*)&h_s[m * HDIM + p * 8 + (k7 & 1) * 4] = tmp[k];
        }
      }
    }
    __syncthreads();
    if (pf) idx_s[(t + 1) & 1][tid] = myidx;

    if (w < 2 && !last) {
      // gates: D[64 gate-rows x 32 batches], 2 waves of mfma_32x32x16,
      // two independent accumulator chains (halve dependent-MFMA latency)
      const int b = lane & 31, half = lane >> 5;
      const int w2h = w * 2 + half;
      f32x16 acc, acc2;
      {
        const int id0 = idx_s[t & 1][b];
        const ushort_t* wp = &wih_s[id0 * WIHP + w2h * 16];
        bf16x8 g0 = *(const bf16x8*)wp;
        bf16x8 g1 = *(const bf16x8*)(wp + 8);
#pragma unroll
        for (int r = 0; r < 8; ++r) {
          acc[r] = bias_s[w2h * 16 + r] + bf2f((ushort_t)g0[r]);
          acc[8 + r] = bias_s[w2h * 16 + 8 + r] + bf2f((ushort_t)g1[r]);
          acc2[r] = 0.f;
          acc2[8 + r] = 0.f;
        }
      }
      const ushort_t* hrow = &h_s[b * HDIM];
      const int bx = b & 7;
#pragma unroll
      for (int kt = 0; kt < 16; ++kt) {
        bf16x8 b0 = *(const bf16x8*)(hrow + ((4 * kt + half) ^ bx) * 8);
        bf16x8 b1 = *(const bf16x8*)(hrow + ((4 * kt + 2 + half) ^ bx) * 8);
        acc = __builtin_amdgcn_mfma_f32_32x32x16_bf16(afrag[2 * kt], b0, acc, 0, 0, 0);
        acc2 = __builtin_amdgcn_mfma_f32_32x32x16_bf16(afrag[2 * kt + 1], b1, acc2, 0, 0, 0);
      }
      // acc[s*4+g]+acc2: gate g, unit 2s+half (of wave's 8 units), batch b
      unsigned hv[4];
#pragma unroll
      for (int s = 0; s < 4; ++s) {
        float ig = acc[s * 4 + 0] + acc2[s * 4 + 0];
        float fg = acc[s * 4 + 1] + acc2[s * 4 + 1];
        float gg = acc[s * 4 + 2] + acc2[s * 4 + 2];
        float og = acc[s * 4 + 3] + acc2[s * 4 + 3];
        float cn = sigmoidf_(fg) * cst[s] + sigmoidf_(ig) * tanhf_(gg);
        cst[s] = cn;
        hv[s] = f2bf(sigmoidf_(og) * tanhf_(cn));
      }
      u64_t own = (u64_t)hv[0] | ((u64_t)hv[1] << 16) | ((u64_t)hv[2] << 32) |
                  ((u64_t)hv[3] << 48);
      u64_t par = (u64_t)__shfl_xor((long long)own, 32, 64);  // partner: half^1
      u64_t out = 0;
#pragma unroll
      for (int j = 0; j < 4; ++j) {  // pack units 4*half+j of this wave's group
        int u4 = 4 * half + j;
        int sidx = 2 * half + (j >> 1);
        u64_t sv = ((u4 & 1) == half) ? own : par;
        out |= ((sv >> (16 * sidx)) & 0xFFFFull) << (16 * j);
      }
      __hip_atomic_store(
          hbq + ((size_t)((t + 1) & 1) * BDIM + bg * BB + b) * 128 + hs * 4 + w * 2 + half,
          out, __ATOMIC_RELAXED, __HIP_MEMORY_SCOPE_AGENT);
      __asm__ volatile("s_waitcnt vmcnt(0)" ::: "memory");  // wave's h at LLC
      if (lane == 0)
        __hip_atomic_store(&flags[bg * 64 + hs * 2 + w], (unsigned)(t + 1),
                           __ATOMIC_RELAXED, __HIP_MEMORY_SCOPE_AGENT);
    } else if (w == 4 && proj_on) {
      // proj: vocab rows hs*4..hs*4+3 x 32 batches, 2 tiles of mfma_16x16x32
      const int n = lane & 15, q = lane >> 4;
      f32x4 acc0 = {0.f, 0.f, 0.f, 0.f};
      f32x4 acc1 = {0.f, 0.f, 0.f, 0.f};
#pragma unroll
      for (int kt = 0; kt < 16; ++kt) {
        const int po = ((kt * 4 + q) ^ (n & 7)) * 8;
        bf16x8 b0 = *(const bf16x8*)&h_s[n * HDIM + po];
        bf16x8 b1 = *(const bf16x8*)&h_s[(16 + n) * HDIM + po];
        acc0 = __builtin_amdgcn_mfma_f32_16x16x32_bf16(afrag[kt], b0, acc0, 0, 0, 0);
        acc1 = __builtin_amdgcn_mfma_f32_16x16x32_bf16(afrag[kt], b1, acc1, 0, 0, 0);
      }
      if (q == 0) {  // rows 0..3 = reg = vocab hs*4+reg
        const int ld = t - 513;
        u64_t q0 = 0, q1 = 0;
#pragma unroll
        for (int r = 0; r < 4; ++r) {
          q0 |= (u64_t)f2bf(acc0[r] + pb_s[r]) << (16 * r);
          q1 |= (u64_t)f2bf(acc1[r] + pb_s[r]) << (16 * r);
        }
        u64_t* lq = (u64_t*)logits;
        const size_t base = ((size_t)ld * BDIM + bg * BB) * 32 + hs;
        lq[base + (size_t)n * 32] = q0;
        lq[base + (size_t)(16 + n) * 32] = q1;
      }
    }
    __syncthreads();  // local h_s reuse guard (NOT on producer->flag path)
  }
}

__global__ void loss_kernel(const ushort_t* __restrict__ logits, const int* __restrict__ E,
                            float* __restrict__ partial) {
  const int t = blockIdx.x;   // 512
  const int b = threadIdx.x;  // 256
  const ushort_t* row = logits + ((size_t)t * BDIM + b) * VDIM;
  float mx = -3.0e38f;
  for (int k = 0; k < VDIM; ++k) mx = fmaxf(mx, bf2f(row[k]));
  float se = 0.f;
  for (int k = 0; k < VDIM; ++k) se += __expf(bf2f(row[k]) - mx);
  const int tgt = E[(size_t)b * (SDIM + 1) + t];
  float nll = (mx + __logf(se)) - bf2f(row[tgt]);
  float m = (tgt != 0) ? 1.f : 0.f;
  __shared__ float s1[BDIM];
  __shared__ float s0[BDIM];
  s1[b] = nll * m;
  s0[b] = m;
  __syncthreads();
  for (int s = 128; s > 0; s >>= 1) {
    if (b < s) {
      s1[b] += s1[b + s];
      s0[b] += s0[b + s];
    }
    __syncthreads();
  }
  if (b == 0) partial[t] = (s0[0] > 0.f) ? s1[0] / s0[0] : 0.f;
}

__global__ void reduce_kernel(const float* __restrict__ partial, float* __restrict__ out) {
  __shared__ float sm[SDIM];
  sm[threadIdx.x] = partial[threadIdx.x];
  __syncthreads();
  for (int s = 256; s > 0; s >>= 1) {
    if (threadIdx.x < s) sm[threadIdx.x] += sm[threadIdx.x + s];
    __syncthreads();
  }
  if (threadIdx.x == 0) out[0] = sm[0];
}

extern "C" void kernel_launch(void* const* d_in, const int* in_sizes, int n_in,
                              void* d_out, int out_size, void* d_ws, size_t ws_size,
                              hipStream_t stream) {
  const int* C_idx = (const int*)d_in[0];
  const int* E = (const int*)d_in[1];
  const float* eWih = (const float*)d_in[2];
  const float* eWhh = (const float*)d_in[3];
  const float* ebi = (const float*)d_in[4];
  const float* ebh = (const float*)d_in[5];
  const float* dWih = (const float*)d_in[6];
  const float* dWhh = (const float*)d_in[7];
  const float* dbi = (const float*)d_in[8];
  const float* dbh = (const float*)d_in[9];
  const float* pW = (const float*)d_in[10];
  const float* pb = (const float*)d_in[11];

  char* ws = (char*)d_ws;
  unsigned* flags = (unsigned*)ws;                      // 8*64*4 B (pad to 4096)
  u64_t* hbq = (u64_t*)(ws + 4096);                     // 2*256*128*8 = 512 KiB
  ushort_t* logits = (ushort_t*)(ws + 4096 + 524288);   // 512*256*128*2 = 32 MiB
  float* partial = (float*)(ws + 4096 + 524288 + 33554432);  // 512*4 B

  // zero flags + h buffer 0 (h(0)=0); ws is poisoned 0xAA each call
  hipMemsetAsync(d_ws, 0, 4096 + 262144, stream);
  lstm_kernel<<<256, NT, 0, stream>>>(C_idx, E, eWih, eWhh, ebi, ebh, dWih, dWhh, dbi, dbh,
                                      pW, pb, flags, hbq, logits);
  loss_kernel<<<512, 256, 0, stream>>>(logits, E, partial);
  reduce_kernel<<<1, 512, 0, stream>>>(partial, (float*)d_out);
}